// Round 1
// baseline (222.044 us; speedup 1.0000x reference)
//
#include <hip/hip_runtime.h>

// Problem constants
#define BQ 4
#define SQ 4096
#define HIDN 768
#define NH 12
#define DH 64
#define BH (BQ * NH)          // 48
#define WIN 128
#define MROWS (BQ * SQ)       // 16384
#define NCOLS (3 * HIDN)      // 2304
#define KDIM HIDN             // 768
#define BHD_ELEMS (BH * SQ * DH)   // 12582912

using bfrag = __attribute__((ext_vector_type(8))) short;   // 8 bf16 (4 VGPRs)
using f32x4 = __attribute__((ext_vector_type(4))) float;   // 4 fp32 acc

__device__ __forceinline__ unsigned short f2bf(float f) {
  union { float f; unsigned u; } x; x.f = f;
  unsigned r = x.u + 0x7fffu + ((x.u >> 16) & 1u);   // RNE
  return (unsigned short)(r >> 16);
}

// ---------------- kernel 0: convert Wq|Wk|Wv fp32 -> bf16 [2304][768] ----------------
__global__ __launch_bounds__(256) void wconv_kernel(
    const float* __restrict__ Wq, const float* __restrict__ Wk,
    const float* __restrict__ Wv, unsigned short* __restrict__ wb)
{
  int i = blockIdx.x * 256 + threadIdx.x;           // one thread = 4 elems
  int g = i * 4;
  if (g >= NCOLS * KDIM) return;
  int n = g / KDIM, k = g - n * KDIM;
  int wsel = n / HIDN, nl = n - wsel * HIDN;
  const float* W = (wsel == 0) ? Wq : (wsel == 1) ? Wk : Wv;
  float4 v = *reinterpret_cast<const float4*>(&W[nl * KDIM + k]);
  ushort4 p;
  p.x = f2bf(v.x); p.y = f2bf(v.y); p.z = f2bf(v.z); p.w = f2bf(v.w);
  *reinterpret_cast<ushort4*>(&wb[g]) = p;
}

// ---------------- kernel 1: fused QKV projection (bf16 MFMA GEMM) ----------------
// C[m][n] = sum_k hid[m][k]*W[n][k] + bias[n]; M=16384 N=2304 K=768
// scatter to qb/kb/vb [48][4096][64] bf16; q pre-scaled by 0.125
#define BM 128
#define BN 128
#define BKK 32
#define LDK 40     // +8 pad: 80B row stride -> 2-way LDS conflicts (free)

__global__ __launch_bounds__(256) void proj_kernel(
    const float* __restrict__ hid,
    const unsigned short* __restrict__ wb,
    const float* __restrict__ bq, const float* __restrict__ bk,
    const float* __restrict__ bv,
    unsigned short* __restrict__ qb, unsigned short* __restrict__ kb,
    unsigned short* __restrict__ vb)
{
  __shared__ unsigned short As[BM][LDK];
  __shared__ unsigned short Bs[BN][LDK];

  const int t = threadIdx.x;
  const int bx = blockIdx.x;            // N tile 0..17 (fastest -> A-panel L2 reuse)
  const int by = blockIdx.y;            // M tile 0..127
  const int m0 = by * BM;
  const int n0 = bx * BN;
  const int wsel = bx / 6;              // 0=q 1=k 2=v (each 6 N-tiles)
  const float* bias = (wsel == 0) ? bq : (wsel == 1) ? bk : bv;
  const int nloc0 = n0 - wsel * HIDN;

  const int lane = t & 63;
  const int w = t >> 6;
  const int wm = w >> 1, wn = w & 1;
  const int fr = lane & 15, fq = lane >> 4;

  f32x4 acc[4][4] = {};

  for (int kt = 0; kt < KDIM / BKK; ++kt) {
    const int k0 = kt * BKK;
    __syncthreads();
    // stage A (fp32 -> bf16 in-register): 128x32, thread handles 4 quads
    #pragma unroll
    for (int i = 0; i < 4; ++i) {
      int s = t + i * 256;
      int row = s >> 3, cg = (s & 7) * 4;
      float4 va = *reinterpret_cast<const float4*>(&hid[(m0 + row) * KDIM + k0 + cg]);
      ushort4 pa;
      pa.x = f2bf(va.x); pa.y = f2bf(va.y); pa.z = f2bf(va.z); pa.w = f2bf(va.w);
      *reinterpret_cast<ushort4*>(&As[row][cg]) = pa;
    }
    // stage B (already bf16): 128x32, thread handles 2 octets
    #pragma unroll
    for (int i = 0; i < 2; ++i) {
      int s = t + i * 256;
      int row = s >> 2, gg = (s & 3) * 8;
      uint4 vb8 = *reinterpret_cast<const uint4*>(&wb[(n0 + row) * KDIM + k0 + gg]);
      *reinterpret_cast<uint4*>(&Bs[row][gg]) = vb8;
    }
    __syncthreads();
    bfrag a[4], b[4];
    #pragma unroll
    for (int i = 0; i < 4; ++i)
      a[i] = *reinterpret_cast<const bfrag*>(&As[wm * 64 + i * 16 + fr][fq * 8]);
    #pragma unroll
    for (int j = 0; j < 4; ++j)
      b[j] = *reinterpret_cast<const bfrag*>(&Bs[wn * 64 + j * 16 + fr][fq * 8]);
    #pragma unroll
    for (int i = 0; i < 4; ++i)
      #pragma unroll
      for (int j = 0; j < 4; ++j)
        acc[i][j] = __builtin_amdgcn_mfma_f32_16x16x32_bf16(a[i], b[j], acc[i][j], 0, 0, 0);
  }

  unsigned short* outb = (wsel == 0) ? qb : (wsel == 1) ? kb : vb;
  const float qscale = (wsel == 0) ? 0.125f : 1.0f;   // fold 1/sqrt(64) into q
  const int b_ = m0 >> 12;                             // batch (BM | 4096)
  #pragma unroll
  for (int j = 0; j < 4; ++j) {
    int nl = nloc0 + wn * 64 + j * 16 + fr;            // col = lane&15
    int h = nl >> 6, d = nl & 63;
    float bsv = bias[nl];
    unsigned short* obase = outb + ((b_ * NH + h) * SQ) * DH + d;
    #pragma unroll
    for (int i = 0; i < 4; ++i)
      #pragma unroll
      for (int r = 0; r < 4; ++r) {
        int m = m0 + wm * 64 + i * 16 + fq * 4 + r;    // row = (lane>>4)*4+r
        int srow = m & (SQ - 1);
        obase[srow * DH] = f2bf((acc[i][j][r] + bsv) * qscale);
      }
  }
}

// ---------------- kernel 2: sliding-window attention ----------------
// block = (head bh, 64-query chunk c); 4 waves x 16 queries
// swapped QK^T: mfma(Kfrag, Qfrag) -> D[key][q]; PV via per-wave P-LDS roundtrip
#define VLD 344    // 320 real keys + 24 pad cols (zeroed); 688B stride, 16B-aligned

__global__ __launch_bounds__(256) void attn_kernel(
    const unsigned short* __restrict__ qb,
    const unsigned short* __restrict__ kb,
    const unsigned short* __restrict__ vb,
    float* __restrict__ out)
{
  __shared__ unsigned short Vt[DH][VLD];       // V^T for this block's key range
  __shared__ unsigned short Pl[4][2][16][40];  // per-wave double-buffered P tile

  const int bh = blockIdx.x;
  const int c = blockIdx.y;
  const int t = threadIdx.x;
  const int lane = t & 63;
  const int w = t >> 6;
  const int b_ = bh / NH, h = bh - b_ * NH;
  const int fr = lane & 15, fq = lane >> 4;

  const unsigned short* Qbh = qb + bh * (SQ * DH);
  const unsigned short* Kbh = kb + bh * (SQ * DH);
  const unsigned short* Vbh = vb + bh * (SQ * DH);

  const int kstart = c * 64 - WIN;             // block key range: [kstart, kstart+320)

  // stage V^T (zero OOB + pad cols so 0*garbage can't make NaN)
  for (int g = t; g < 16 * VLD; g += 256) {
    int key = g >> 4;
    int dg = (g & 15) * 4;
    int krow = kstart + key;
    ushort4 vv = {0, 0, 0, 0};
    if (key < 320 && krow >= 0 && krow < SQ)
      vv = *reinterpret_cast<const ushort4*>(&Vbh[krow * DH + dg]);
    Vt[dg + 0][key] = vv.x; Vt[dg + 1][key] = vv.y;
    Vt[dg + 2][key] = vv.z; Vt[dg + 3][key] = vv.w;
  }
  __syncthreads();

  const int q0 = c * 64 + w * 16;              // this wave's 16 queries
  const int kw = q0 - WIN;                     // wave key range start (17 tiles)
  bfrag qf0 = *reinterpret_cast<const bfrag*>(&Qbh[(q0 + fr) * DH + fq * 8]);
  bfrag qf1 = *reinterpret_cast<const bfrag*>(&Qbh[(q0 + fr) * DH + 32 + fq * 8]);

  float sc[17][4];
  #pragma unroll
  for (int tt = 0; tt < 17; ++tt) {
    int krow = kw + tt * 16 + fr;
    int kc = krow < 0 ? 0 : (krow >= SQ ? SQ - 1 : krow);   // clamp; masked later
    bfrag kf0 = *reinterpret_cast<const bfrag*>(&Kbh[kc * DH + fq * 8]);
    bfrag kf1 = *reinterpret_cast<const bfrag*>(&Kbh[kc * DH + 32 + fq * 8]);
    f32x4 d = {};
    d = __builtin_amdgcn_mfma_f32_16x16x32_bf16(kf0, qf0, d, 0, 0, 0);
    d = __builtin_amdgcn_mfma_f32_16x16x32_bf16(kf1, qf1, d, 0, 0, 0);
    #pragma unroll
    for (int r = 0; r < 4; ++r) sc[tt][r] = d[r];
  }

  // mask: |key - q| <= 128 and key in [0,S)
  const int q = q0 + fr;                       // this lane's query (col)
  #pragma unroll
  for (int tt = 0; tt < 17; ++tt)
    #pragma unroll
    for (int r = 0; r < 4; ++r) {
      int key = kw + tt * 16 + fq * 4 + r;     // row = (lane>>4)*4+r
      int dk = key - q;
      bool valid = (dk >= -WIN) && (dk <= WIN) && (key >= 0) && (key < SQ);
      if (!valid) sc[tt][r] = -1e30f;
    }

  // softmax over the row (q fixed per lane&15; partners at lane^16, lane^32)
  float mx = -1e30f;
  #pragma unroll
  for (int tt = 0; tt < 17; ++tt)
    #pragma unroll
    for (int r = 0; r < 4; ++r) mx = fmaxf(mx, sc[tt][r]);
  mx = fmaxf(mx, __shfl_xor(mx, 16));
  mx = fmaxf(mx, __shfl_xor(mx, 32));

  float sum = 0.f;
  #pragma unroll
  for (int tt = 0; tt < 17; ++tt)
    #pragma unroll
    for (int r = 0; r < 4; ++r) {
      float p = __expf(sc[tt][r] - mx);
      sc[tt][r] = p;
      sum += p;
    }
  sum += __shfl_xor(sum, 16);
  sum += __shfl_xor(sum, 32);
  const float rinv = 1.0f / sum;

  // PV: 9 K-steps of 32 keys (last half-tile zero-padded)
  f32x4 ctx[4] = {};
  #pragma unroll
  for (int ks = 0; ks < 9; ++ks) {
    unsigned short (&P)[16][40] = Pl[w][ks & 1];
    #pragma unroll
    for (int half = 0; half < 2; ++half) {
      int tt = ks * 2 + half;
      unsigned p01 = 0, p23 = 0;
      if (tt < 17) {
        p01 = (unsigned)f2bf(sc[tt][0] * rinv) | ((unsigned)f2bf(sc[tt][1] * rinv) << 16);
        p23 = (unsigned)f2bf(sc[tt][2] * rinv) | ((unsigned)f2bf(sc[tt][3] * rinv) << 16);
      }
      *reinterpret_cast<unsigned*>(&P[fr][half * 16 + fq * 4]) = p01;
      *reinterpret_cast<unsigned*>(&P[fr][half * 16 + fq * 4 + 2]) = p23;
    }
    asm volatile("s_waitcnt lgkmcnt(0)" ::: "memory");
    bfrag pa = *reinterpret_cast<const bfrag*>(&P[fr][fq * 8]);
    #pragma unroll
    for (int nt = 0; nt < 4; ++nt) {
      const bfrag vf = *reinterpret_cast<const bfrag*>(
          &Vt[nt * 16 + fr][w * 16 + ks * 32 + fq * 8]);
      ctx[nt] = __builtin_amdgcn_mfma_f32_16x16x32_bf16(pa, vf, ctx[nt], 0, 0, 0);
    }
  }

  // write ctx: row=(lane>>4)*4+r = q, col=lane&15 = d (within nt block)
  #pragma unroll
  for (int nt = 0; nt < 4; ++nt)
    #pragma unroll
    for (int r = 0; r < 4; ++r) {
      int qq = fq * 4 + r;
      int d = nt * 16 + fr;
      out[(size_t)(b_ * SQ + q0 + qq) * HIDN + h * DH + d] = ctx[nt][r];
    }
}

extern "C" void kernel_launch(void* const* d_in, const int* in_sizes, int n_in,
                              void* d_out, int out_size, void* d_ws, size_t ws_size,
                              hipStream_t stream) {
  const float* hid = (const float*)d_in[0];
  const float* Wq  = (const float*)d_in[1];
  const float* bq  = (const float*)d_in[2];
  const float* Wk  = (const float*)d_in[3];
  const float* bk  = (const float*)d_in[4];
  const float* Wv  = (const float*)d_in[5];
  const float* bv  = (const float*)d_in[6];
  float* out = (float*)d_out;

  // ws layout: qb | kb | vb (bf16 [48][4096][64] each) | wb (bf16 [2304][768])
  unsigned short* qb = (unsigned short*)d_ws;
  unsigned short* kb = qb + BHD_ELEMS;
  unsigned short* vb = kb + BHD_ELEMS;
  unsigned short* wb = vb + BHD_ELEMS;

  int nconv = (NCOLS * KDIM / 4 + 255) / 256;
  wconv_kernel<<<dim3(nconv), dim3(256), 0, stream>>>(Wq, Wk, Wv, wb);

  dim3 g1(NCOLS / BN, MROWS / BM);
  proj_kernel<<<g1, dim3(256), 0, stream>>>(hid, wb, bq, bk, bv, qb, kb, vb);

  dim3 g2(BH, SQ / 64);
  attn_kernel<<<g2, dim3(256), 0, stream>>>(qb, kb, vb, out);
}

// Round 2
// 186.404 us; speedup vs baseline: 1.1912x; 1.1912x over previous
//
#include <hip/hip_runtime.h>

// Problem constants
#define BQ 4
#define SQ 4096
#define HIDN 768
#define NH 12
#define DH 64
#define BH (BQ * NH)          // 48
#define WIN 128
#define MROWS (BQ * SQ)       // 16384
#define NCOLS (3 * HIDN)      // 2304
#define KDIM HIDN             // 768
#define BHD_ELEMS (BH * SQ * DH)   // 12582912

using bfrag = __attribute__((ext_vector_type(8))) short;   // 8 bf16 (4 VGPRs)
using f32x4 = __attribute__((ext_vector_type(4))) float;   // 4 fp32 acc

__device__ __forceinline__ unsigned short f2bf(float f) {
  union { float f; unsigned u; } x; x.f = f;
  unsigned r = x.u + 0x7fffu + ((x.u >> 16) & 1u);   // RNE
  return (unsigned short)(r >> 16);
}
__device__ __forceinline__ unsigned f2bf2(float lo, float hi) {
  return (unsigned)f2bf(lo) | ((unsigned)f2bf(hi) << 16);
}

__device__ __forceinline__ void gload16(const void* g, void* l) {
  __builtin_amdgcn_global_load_lds(
      (const __attribute__((address_space(1))) unsigned int*)g,
      (__attribute__((address_space(3))) unsigned int*)l, 16, 0, 0);
}

// ---------------- kernel 0a: convert Wq|Wk|Wv fp32 -> bf16 [2304][768] ----------------
__global__ __launch_bounds__(256) void wconv_kernel(
    const float* __restrict__ Wq, const float* __restrict__ Wk,
    const float* __restrict__ Wv, unsigned short* __restrict__ wb)
{
  int i = blockIdx.x * 256 + threadIdx.x;           // one thread = 4 elems
  int g = i * 4;
  if (g >= NCOLS * KDIM) return;
  int n = g / KDIM, k = g - n * KDIM;
  int wsel = n / HIDN, nl = n - wsel * HIDN;
  const float* W = (wsel == 0) ? Wq : (wsel == 1) ? Wk : Wv;
  float4 v = *reinterpret_cast<const float4*>(&W[nl * KDIM + k]);
  ushort4 p;
  p.x = f2bf(v.x); p.y = f2bf(v.y); p.z = f2bf(v.z); p.w = f2bf(v.w);
  *reinterpret_cast<ushort4*>(&wb[g]) = p;
}

// ---------------- kernel 0b: convert hidden fp32 -> bf16 [16384][768] ----------------
__global__ __launch_bounds__(256) void hconv_kernel(
    const float* __restrict__ hid, unsigned short* __restrict__ hb)
{
  const int N8 = MROWS * KDIM / 8;                  // 1572864 items of 8 elems
  for (int idx = blockIdx.x * 256 + threadIdx.x; idx < N8; idx += gridDim.x * 256) {
    const float4* src = reinterpret_cast<const float4*>(hid) + (size_t)idx * 2;
    float4 a = src[0], b = src[1];
    uint4 o;
    o.x = f2bf2(a.x, a.y); o.y = f2bf2(a.z, a.w);
    o.z = f2bf2(b.x, b.y); o.w = f2bf2(b.z, b.w);
    *reinterpret_cast<uint4*>(&hb[(size_t)idx * 8]) = o;
  }
}

// ---------------- kernel 1: fused QKV projection (bf16 MFMA, m97 structure) ----------------
// C[m][n] = sum_k hb[m][k]*wb[n][k] + bias[n]; M=16384 N=2304 K=768
// global_load_lds (16B) staging into linear [128][32] LDS tiles.
#define BM 128
#define BN 128
#define BKK 32

__global__ __launch_bounds__(256) void proj_kernel(
    const unsigned short* __restrict__ hb,
    const unsigned short* __restrict__ wb,
    const float* __restrict__ bq, const float* __restrict__ bk,
    const float* __restrict__ bv,
    unsigned short* __restrict__ qb, unsigned short* __restrict__ kb,
    unsigned short* __restrict__ vb)
{
  __shared__ unsigned short As[BM][BKK];
  __shared__ unsigned short Bs[BN][BKK];

  const int t = threadIdx.x;
  const int bx = blockIdx.x;            // N tile 0..17 (fastest -> A-panel L2 reuse)
  const int by = blockIdx.y;            // M tile 0..127
  const int m0 = by * BM;
  const int n0 = bx * BN;
  const int wsel = bx / 6;              // 0=q 1=k 2=v (each 6 N-tiles)
  const float* bias = (wsel == 0) ? bq : (wsel == 1) ? bk : bv;
  const int nloc0 = n0 - wsel * HIDN;

  const int lane = t & 63;
  const int w = t >> 6;
  const int wm = w >> 1, wn = w & 1;
  const int fr = lane & 15, fq = lane >> 4;

  // staging: wave w owns rows w*32 .. w*32+31 of both tiles; 2 insts each
  // lane l -> row base + l/4, byte col (l%4)*16; LDS dest = base + lane*16 (linear match)
  const int srow = w * 32 + (lane >> 2);
  const int scol = (lane & 3) * 8;                   // element offset (16B)
  const unsigned short* gA = &hb[(size_t)(m0 + srow) * KDIM + scol];
  const unsigned short* gB = &wb[(size_t)(n0 + srow) * KDIM + scol];
  unsigned short* lA0 = &As[w * 32][0];
  unsigned short* lA1 = &As[w * 32 + 16][0];
  unsigned short* lB0 = &Bs[w * 32][0];
  unsigned short* lB1 = &Bs[w * 32 + 16][0];

  f32x4 acc[4][4] = {};

  for (int kt = 0; kt < KDIM / BKK; ++kt) {
    const int k0 = kt * BKK;
    __syncthreads();                                 // prev compute's ds_reads done
    gload16(gA + k0, lA0);
    gload16(gA + k0 + 16 * KDIM, lA1);
    gload16(gB + k0, lB0);
    gload16(gB + k0 + 16 * KDIM, lB1);
    __syncthreads();                                 // loads landed (vmcnt drain)
    bfrag a[4], b[4];
    #pragma unroll
    for (int i = 0; i < 4; ++i)
      a[i] = *reinterpret_cast<const bfrag*>(&As[wm * 64 + i * 16 + fr][fq * 8]);
    #pragma unroll
    for (int j = 0; j < 4; ++j)
      b[j] = *reinterpret_cast<const bfrag*>(&Bs[wn * 64 + j * 16 + fr][fq * 8]);
    #pragma unroll
    for (int i = 0; i < 4; ++i)
      #pragma unroll
      for (int j = 0; j < 4; ++j)
        acc[i][j] = __builtin_amdgcn_mfma_f32_16x16x32_bf16(a[i], b[j], acc[i][j], 0, 0, 0);
  }

  unsigned short* outb = (wsel == 0) ? qb : (wsel == 1) ? kb : vb;
  const float qscale = (wsel == 0) ? 0.125f : 1.0f;   // fold 1/sqrt(64) into q
  const int b_ = m0 >> 12;                             // batch (BM | 4096)
  #pragma unroll
  for (int j = 0; j < 4; ++j) {
    int nl = nloc0 + wn * 64 + j * 16 + fr;            // col = lane&15
    int h = nl >> 6, d = nl & 63;
    float bsv = bias[nl];
    unsigned short* obase = outb + ((b_ * NH + h) * SQ) * DH + d;
    #pragma unroll
    for (int i = 0; i < 4; ++i)
      #pragma unroll
      for (int r = 0; r < 4; ++r) {
        int m = m0 + wm * 64 + i * 16 + fq * 4 + r;    // row = (lane>>4)*4+r
        int srow_ = m & (SQ - 1);
        obase[srow_ * DH] = f2bf((acc[i][j][r] + bsv) * qscale);
      }
  }
}

// ---------------- kernel 2: sliding-window attention ----------------
// block = (head bh, 64-query chunk c); 4 waves x 16 queries
// swapped QK^T: mfma(Kfrag, Qfrag) -> D[key][q]; PV via per-wave P-LDS roundtrip
#define VLD 344    // 320 real keys + 24 pad cols (zeroed); 688B stride, 8B-aligned packs

__global__ __launch_bounds__(256) void attn_kernel(
    const unsigned short* __restrict__ qb,
    const unsigned short* __restrict__ kb,
    const unsigned short* __restrict__ vb,
    float* __restrict__ out)
{
  __shared__ unsigned short Vt[DH][VLD];       // V^T for this block's key range
  __shared__ unsigned short Pl[4][16][40];     // per-wave P tile

  const int bh = blockIdx.x;
  const int c = blockIdx.y;
  const int t = threadIdx.x;
  const int lane = t & 63;
  const int w = t >> 6;
  const int b_ = bh / NH, h = bh - b_ * NH;
  const int fr = lane & 15, fq = lane >> 4;

  const unsigned short* Qbh = qb + bh * (SQ * DH);
  const unsigned short* Kbh = kb + bh * (SQ * DH);
  const unsigned short* Vbh = vb + bh * (SQ * DH);

  const int kstart = c * 64 - WIN;             // block key range: [kstart, kstart+320)

  // stage V^T: item = (kg 0..85, dg 0..15): 4 keys x 4 d, packed b64 writes
  for (int i = t; i < 86 * 16; i += 256) {
    int kg = i >> 4, dg = i & 15;
    ushort4 v0 = {0,0,0,0}, v1 = {0,0,0,0}, v2 = {0,0,0,0}, v3 = {0,0,0,0};
    int key0 = kg * 4;
    int kr = kstart + key0;
    const unsigned short* vsrc = &Vbh[(size_t)kr * DH + dg * 4];
    if (key0 + 0 < 320 && kr + 0 >= 0 && kr + 0 < SQ) v0 = *reinterpret_cast<const ushort4*>(vsrc + 0 * DH);
    if (key0 + 1 < 320 && kr + 1 >= 0 && kr + 1 < SQ) v1 = *reinterpret_cast<const ushort4*>(vsrc + 1 * DH);
    if (key0 + 2 < 320 && kr + 2 >= 0 && kr + 2 < SQ) v2 = *reinterpret_cast<const ushort4*>(vsrc + 2 * DH);
    if (key0 + 3 < 320 && kr + 3 >= 0 && kr + 3 < SQ) v3 = *reinterpret_cast<const ushort4*>(vsrc + 3 * DH);
    ushort4 p0 = {v0.x, v1.x, v2.x, v3.x};
    ushort4 p1 = {v0.y, v1.y, v2.y, v3.y};
    ushort4 p2 = {v0.z, v1.z, v2.z, v3.z};
    ushort4 p3 = {v0.w, v1.w, v2.w, v3.w};
    *reinterpret_cast<ushort4*>(&Vt[dg * 4 + 0][key0]) = p0;
    *reinterpret_cast<ushort4*>(&Vt[dg * 4 + 1][key0]) = p1;
    *reinterpret_cast<ushort4*>(&Vt[dg * 4 + 2][key0]) = p2;
    *reinterpret_cast<ushort4*>(&Vt[dg * 4 + 3][key0]) = p3;
  }
  __syncthreads();

  const int q0 = c * 64 + w * 16;              // this wave's 16 queries
  const int kw = q0 - WIN;                     // wave key range start (17 tiles)
  bfrag qf0 = *reinterpret_cast<const bfrag*>(&Qbh[(q0 + fr) * DH + fq * 8]);
  bfrag qf1 = *reinterpret_cast<const bfrag*>(&Qbh[(q0 + fr) * DH + 32 + fq * 8]);

  float sc[17][4];
  #pragma unroll
  for (int tt = 0; tt < 17; ++tt) {
    int krow = kw + tt * 16 + fr;
    int kc = krow < 0 ? 0 : (krow >= SQ ? SQ - 1 : krow);   // clamp; masked later
    bfrag kf0 = *reinterpret_cast<const bfrag*>(&Kbh[kc * DH + fq * 8]);
    bfrag kf1 = *reinterpret_cast<const bfrag*>(&Kbh[kc * DH + 32 + fq * 8]);
    f32x4 d = {};
    d = __builtin_amdgcn_mfma_f32_16x16x32_bf16(kf0, qf0, d, 0, 0, 0);
    d = __builtin_amdgcn_mfma_f32_16x16x32_bf16(kf1, qf1, d, 0, 0, 0);
    #pragma unroll
    for (int r = 0; r < 4; ++r) sc[tt][r] = d[r];
  }

  // mask: |key - q| <= 128 and key in [0,S)
  const int q = q0 + fr;                       // this lane's query (col)
  #pragma unroll
  for (int tt = 0; tt < 17; ++tt)
    #pragma unroll
    for (int r = 0; r < 4; ++r) {
      int key = kw + tt * 16 + fq * 4 + r;     // row = (lane>>4)*4+r
      int dk = key - q;
      bool valid = (dk >= -WIN) && (dk <= WIN) && (key >= 0) && (key < SQ);
      if (!valid) sc[tt][r] = -1e30f;
    }

  // softmax over the row (q fixed per lane&15; partners at lane^16, lane^32)
  float mx = -1e30f;
  #pragma unroll
  for (int tt = 0; tt < 17; ++tt)
    #pragma unroll
    for (int r = 0; r < 4; ++r) mx = fmaxf(mx, sc[tt][r]);
  mx = fmaxf(mx, __shfl_xor(mx, 16));
  mx = fmaxf(mx, __shfl_xor(mx, 32));

  float sum = 0.f;
  #pragma unroll
  for (int tt = 0; tt < 17; ++tt)
    #pragma unroll
    for (int r = 0; r < 4; ++r) {
      float p = __expf(sc[tt][r] - mx);
      sc[tt][r] = p;
      sum += p;
    }
  sum += __shfl_xor(sum, 16);
  sum += __shfl_xor(sum, 32);
  const float rinv = 1.0f / sum;

  // PV: 9 K-steps of 32 keys (last half-tile zero-padded)
  f32x4 ctx[4] = {};
  #pragma unroll
  for (int ks = 0; ks < 9; ++ks) {
    unsigned short (&P)[16][40] = Pl[w];
    #pragma unroll
    for (int half = 0; half < 2; ++half) {
      int tt = ks * 2 + half;
      unsigned p01 = 0, p23 = 0;
      if (tt < 17) {
        p01 = f2bf2(sc[tt][0] * rinv, sc[tt][1] * rinv);
        p23 = f2bf2(sc[tt][2] * rinv, sc[tt][3] * rinv);
      }
      *reinterpret_cast<unsigned*>(&P[fr][half * 16 + fq * 4]) = p01;
      *reinterpret_cast<unsigned*>(&P[fr][half * 16 + fq * 4 + 2]) = p23;
    }
    asm volatile("s_waitcnt lgkmcnt(0)" ::: "memory");
    bfrag pa = *reinterpret_cast<const bfrag*>(&P[fr][fq * 8]);
    #pragma unroll
    for (int nt = 0; nt < 4; ++nt) {
      const bfrag vf = *reinterpret_cast<const bfrag*>(
          &Vt[nt * 16 + fr][w * 16 + ks * 32 + fq * 8]);
      ctx[nt] = __builtin_amdgcn_mfma_f32_16x16x32_bf16(pa, vf, ctx[nt], 0, 0, 0);
    }
  }

  // write ctx: row=(lane>>4)*4+r = q, col=lane&15 = d (within nt block)
  #pragma unroll
  for (int nt = 0; nt < 4; ++nt)
    #pragma unroll
    for (int r = 0; r < 4; ++r) {
      int qq = fq * 4 + r;
      int d = nt * 16 + fr;
      out[(size_t)(b_ * SQ + q0 + qq) * HIDN + h * DH + d] = ctx[nt][r];
    }
}

extern "C" void kernel_launch(void* const* d_in, const int* in_sizes, int n_in,
                              void* d_out, int out_size, void* d_ws, size_t ws_size,
                              hipStream_t stream) {
  const float* hid = (const float*)d_in[0];
  const float* Wq  = (const float*)d_in[1];
  const float* bq  = (const float*)d_in[2];
  const float* Wk  = (const float*)d_in[3];
  const float* bk  = (const float*)d_in[4];
  const float* Wv  = (const float*)d_in[5];
  const float* bv  = (const float*)d_in[6];
  float* out = (float*)d_out;

  // ws layout: qb | kb | vb (bf16 [48][4096][64] each) | wb bf16 [2304][768] | hb bf16 [16384][768]
  unsigned short* qb = (unsigned short*)d_ws;
  unsigned short* kb = qb + BHD_ELEMS;
  unsigned short* vb = kb + BHD_ELEMS;
  unsigned short* wb = vb + BHD_ELEMS;
  unsigned short* hb = wb + NCOLS * KDIM;

  int nconv = (NCOLS * KDIM / 4 + 255) / 256;
  wconv_kernel<<<dim3(nconv), dim3(256), 0, stream>>>(Wq, Wk, Wv, wb);
  hconv_kernel<<<dim3(2048), dim3(256), 0, stream>>>(hid, hb);

  dim3 g1(NCOLS / BN, MROWS / BM);
  proj_kernel<<<g1, dim3(256), 0, stream>>>(hb, wb, bq, bk, bv, qb, kb, vb);

  dim3 g2(BH, SQ / 64);
  attn_kernel<<<g2, dim3(256), 0, stream>>>(qb, kb, vb, out);
}